// Round 1
// baseline (149.500 us; speedup 1.0000x reference)
//
#include <hip/hip_runtime.h>
#include <hip/hip_bf16.h>

// MXEPLoss: analytic reduction of the reference.
// Inputs (dict order): xq [Nq,D] f32, yq [Nq] i32, xs [Ns,D] f32, ys [Ns] i32, pos [Nq] i32
// Fixed shapes for this bench: Nq=Ns=4096, D=1024, K=128.
// Output: scalar f32 loss.
//
// Key identities (T=1, INF never actually contributes because the masked entry
// is exactly the one removed from the mask):
//   pos_logit[i] = -(1/2) [ cnt*q2 - 2 xq.mus[cl] + S2[cl] - own_i ] / (cnt - [own&idx])
//   mus[c] = proto_n[c] * clip(cnt,0.1)  ->  xq.mus comes free from the dots matmul
//   d_pos^2 = q2 - 2(xq.M)/Ccl + |M|^2/Ccl^2,  M = mus[ci]-xq,  Ccl=clip(cnt-1,0.1)

#define KCLS 128
#define QB 16
#define BK 32

__global__ __launch_bounds__(256) void class_stats_kernel(
    const float* __restrict__ xs, const int* __restrict__ ys,
    int Ns, int D,
    float* __restrict__ protoT, float* __restrict__ S2,
    float* __restrict__ mu2v, float* __restrict__ pn2v, int* __restrict__ cntArr)
{
    const int c = blockIdx.x;     // class
    const int t = threadIdx.x;    // 0..255 ; D assumed 1024 (4 dims/thread)
    __shared__ int list[4096];
    __shared__ int lcnt;
    __shared__ float red[256];
    if (t == 0) lcnt = 0;
    __syncthreads();
    for (int s = t; s < Ns; s += 256) {
        if (ys[s] == c) list[atomicAdd(&lcnt, 1)] = s;
    }
    __syncthreads();
    const int n = lcnt;
    float a0 = 0.f, a1 = 0.f, a2 = 0.f, a3 = 0.f, s2p = 0.f;
    for (int r = 0; r < n; ++r) {
        const float* row = xs + (size_t)list[r] * D;
        float x0 = row[t], x1 = row[t + 256], x2 = row[t + 512], x3 = row[t + 768];
        a0 += x0; a1 += x1; a2 += x2; a3 += x3;
        s2p += x0 * x0 + x1 * x1 + x2 * x2 + x3 * x3;
    }
    const float clipc = fmaxf((float)n, 0.1f);
    const float inv = 1.0f / clipc;
    protoT[(size_t)(t      ) * KCLS + c] = a0 * inv;
    protoT[(size_t)(t + 256) * KCLS + c] = a1 * inv;
    protoT[(size_t)(t + 512) * KCLS + c] = a2 * inv;
    protoT[(size_t)(t + 768) * KCLS + c] = a3 * inv;
    float mu2p = a0 * a0 + a1 * a1 + a2 * a2 + a3 * a3;
    red[t] = mu2p; __syncthreads();
    for (int o = 128; o > 0; o >>= 1) { if (t < o) red[t] += red[t + o]; __syncthreads(); }
    const float mu2s = red[0];
    __syncthreads();
    red[t] = s2p; __syncthreads();
    for (int o = 128; o > 0; o >>= 1) { if (t < o) red[t] += red[t + o]; __syncthreads(); }
    if (t == 0) {
        mu2v[c] = mu2s;
        pn2v[c] = mu2s * inv * inv;
        S2[c]   = red[0];
        cntArr[c] = n;
    }
}

__global__ __launch_bounds__(256) void own_kernel(
    const float* __restrict__ xq, const float* __restrict__ xs,
    const int* __restrict__ posA, int Nq, int D, float* __restrict__ ownA)
{
    const int wave = threadIdx.x >> 6;
    const int lane = threadIdx.x & 63;
    const int i = blockIdx.x * 4 + wave;
    if (i >= Nq) return;
    const float* q = xq + (size_t)i * D;
    const float* s = xs + (size_t)posA[i] * D;
    float acc = 0.f;
    for (int k = lane * 4; k < D; k += 256) {
        float4 a = *(const float4*)(q + k);
        float4 b = *(const float4*)(s + k);
        float dx = a.x - b.x, dy = a.y - b.y, dz = a.z - b.z, dw = a.w - b.w;
        acc += dx * dx + dy * dy + dz * dz + dw * dw;
    }
    for (int o = 32; o > 0; o >>= 1) acc += __shfl_down(acc, o);
    if (lane == 0) ownA[i] = acc;
}

__global__ __launch_bounds__(256) void main_kernel(
    const float* __restrict__ xq, const int* __restrict__ yq,
    const int* __restrict__ ys, const int* __restrict__ posA,
    const float* __restrict__ protoT, const float* __restrict__ S2,
    const float* __restrict__ mu2v, const float* __restrict__ pn2v,
    const int* __restrict__ cntArr, const float* __restrict__ ownA,
    int Nq, int D, float invNq, float* __restrict__ out)
{
    const int t  = threadIdx.x;
    const int qg = t >> 4;       // query slot 0..15
    const int cg = t & 15;       // class group: classes cg*8 .. cg*8+7
    const int qi = blockIdx.x * QB + qg;

    __shared__ float As[QB * BK];       // [q][k]
    __shared__ float Bs[BK * KCLS];     // [k][c]
    __shared__ float dotsS[QB][KCLS];
    __shared__ float diffS[QB];

    float acc[8] = {0.f,0.f,0.f,0.f,0.f,0.f,0.f,0.f};
    float q2 = 0.f;
    const float* qbase = xq + (size_t)blockIdx.x * QB * D;

    for (int kb = 0; kb < D; kb += BK) {
        {   // A tile: 16q x 32k, float2 per thread, coalesced per query row
            const int q = t >> 4, k0 = (t & 15) * 2;
            const float2 av = *(const float2*)(qbase + (size_t)q * D + kb + k0);
            As[q * BK + k0]     = av.x;
            As[q * BK + k0 + 1] = av.y;
        }
        {   // B tile: 32k x 128c = 4096 floats, contiguous in protoT
            const float* gB = protoT + (size_t)kb * KCLS;
            #pragma unroll
            for (int r = 0; r < 4; ++r) {
                float4 bv = *(const float4*)(gB + (t + 256 * r) * 4);
                *(float4*)(Bs + (t + 256 * r) * 4) = bv;
            }
        }
        __syncthreads();
        #pragma unroll
        for (int k4 = 0; k4 < BK; k4 += 4) {
            const float4 a4 = *(const float4*)(As + qg * BK + k4);
            const float* brow = Bs + k4 * KCLS + cg * 8;
            #pragma unroll
            for (int kk = 0; kk < 4; ++kk) {
                const float a = (&a4.x)[kk];
                q2 += a * a;
                const float4 b0 = *(const float4*)(brow + kk * KCLS);
                const float4 b1 = *(const float4*)(brow + kk * KCLS + 4);
                acc[0] += a * b0.x; acc[1] += a * b0.y;
                acc[2] += a * b0.z; acc[3] += a * b0.w;
                acc[4] += a * b1.x; acc[5] += a * b1.y;
                acc[6] += a * b1.z; acc[7] += a * b1.w;
            }
        }
        __syncthreads();
    }

    #pragma unroll
    for (int j = 0; j < 8; ++j) dotsS[qg][cg * 8 + j] = acc[j];
    __syncthreads();

    // ---- per-query scalars (computed redundantly by all 16 threads of a query) ----
    const int p  = posA[qi];
    const int ci = ys[p];                       // yq_new
    const int cnt_i = cntArr[ci];
    const float cnt_ci  = (float)cnt_i;
    const float clip_ci = fmaxf(cnt_ci, 0.1f);
    const float dotmu   = dotsS[qg][ci] * clip_ci;   // xq . mus[ci]
    const float Ccl     = fmaxf(cnt_ci - 1.0f, 0.1f);
    const float dqM     = dotmu - q2;                // xq . (mus-xq)
    const float M2      = mu2v[ci] - 2.f * dotmu + q2;
    const float dpos2   = q2 - 2.f * dqM / Ccl + M2 / (Ccl * Ccl);
    const float d_pos   = sqrtf(fmaxf(dpos2, 0.f) + 1e-12f);

    // ---- logsumexp over 128 classes (8 per thread, 16 threads per query) ----
    float ld[8];
    float m = -3.0e38f;
    #pragma unroll
    for (int j = 0; j < 8; ++j) {
        const int c = cg * 8 + j;
        const float sq = fmaxf(q2 + pn2v[c] - 2.f * acc[j], 0.f) + 1e-12f;
        float v = -sqrtf(sq);
        if (c == ci) v = -d_pos;
        ld[j] = v;
        m = fmaxf(m, v);
    }
    #pragma unroll
    for (int o = 1; o < 16; o <<= 1) m = fmaxf(m, __shfl_xor(m, o));
    float se = 0.f;
    #pragma unroll
    for (int j = 0; j < 8; ++j) se += expf(ld[j] - m);
    #pragma unroll
    for (int o = 1; o < 16; o <<= 1) se += __shfl_xor(se, o);
    const float lse = m + logf(se);

    if (cg == 0) {
        const int cl = yq[qi];
        const int cntl_i = cntArr[cl];
        const float cntl   = (float)cntl_i;
        const float clip_l = fmaxf(cntl, 0.1f);
        const float dotmu_l = dotsS[qg][cl] * clip_l;       // xq . mus[cl]
        const float sum_sqd = cntl * q2 - 2.f * dotmu_l + S2[cl];
        const bool m_own = (cl == ci);                      // yq[i] == ys[pos[i]]
        const bool idxq  = (cntl_i > 1);
        const float numer = -0.5f * (sum_sqd - (m_own ? ownA[qi] : 0.f));
        const float denom = cntl - ((m_own && idxq) ? 1.f : 0.f);
        const float pl = numer / denom;
        diffS[qg] = lse - pl;
    }
    __syncthreads();
    if (t == 0) {
        float ssum = 0.f;
        #pragma unroll
        for (int q = 0; q < QB; ++q) ssum += diffS[q];
        atomicAdd(out, ssum * invNq);
    }
}

extern "C" void kernel_launch(void* const* d_in, const int* in_sizes, int n_in,
                              void* d_out, int out_size, void* d_ws, size_t ws_size,
                              hipStream_t stream) {
    const float* xq  = (const float*)d_in[0];
    const int*   yq  = (const int*)d_in[1];
    const float* xs  = (const float*)d_in[2];
    const int*   ys  = (const int*)d_in[3];
    const int*   pos = (const int*)d_in[4];

    const int Nq = in_sizes[1];
    const int Ns = in_sizes[3];
    const int D  = in_sizes[0] / Nq;   // 1024

    char* w = (char*)d_ws;
    float* protoT = (float*)w;  w += (size_t)D * KCLS * sizeof(float);   // proto_n^T [D][K]
    float* S2     = (float*)w;  w += KCLS * sizeof(float);
    float* mu2v   = (float*)w;  w += KCLS * sizeof(float);
    float* pn2v   = (float*)w;  w += KCLS * sizeof(float);
    int*   cntA   = (int*)w;    w += KCLS * sizeof(int);
    float* ownA   = (float*)w;  w += (size_t)Nq * sizeof(float);

    float* out = (float*)d_out;
    hipMemsetAsync(out, 0, (size_t)out_size * sizeof(float), stream);

    class_stats_kernel<<<KCLS, 256, 0, stream>>>(xs, ys, Ns, D, protoT, S2, mu2v, pn2v, cntA);
    own_kernel<<<(Nq + 3) / 4, 256, 0, stream>>>(xq, xs, pos, Nq, D, ownA);
    main_kernel<<<Nq / QB, 256, 0, stream>>>(xq, yq, ys, pos, protoT, S2, mu2v, pn2v,
                                             cntA, ownA, Nq, D, 1.0f / (float)Nq, out);
}

// Round 2
// 106.760 us; speedup vs baseline: 1.4003x; 1.4003x over previous
//
#include <hip/hip_runtime.h>
#include <hip/hip_bf16.h>

// MXEPLoss analytic + MFMA-bf16 dots GEMM.
// Inputs: xq [Nq,D] f32, yq [Nq] i32, xs [Ns,D] f32, ys [Ns] i32, pos [Nq] i32
// Shapes fixed by bench: Nq=Ns=4096, D=1024, K=128 classes. Output: scalar f32.
//
// dots[q][c] = xq[q] . proto_n[c]  via mfma_f32_16x16x32_bf16.
// Exact-sensitive scalars (q2, own, S2, mu2, cnt) stay fp32; only dots is bf16
// (error ~0.05 on loss vs threshold 19.92).

#define KCLS 128
#define QB 16
#define BK 64

typedef __attribute__((ext_vector_type(8))) short short8;
typedef __attribute__((ext_vector_type(4))) float f32x4;

__device__ __forceinline__ short f2bs(float f) {
    __hip_bfloat16 h = __float2bfloat16(f);
    short s; __builtin_memcpy(&s, &h, 2); return s;
}

// ---------------- class stats: 512 blocks = 128 classes x 4 dim-quarters ----
__global__ __launch_bounds__(256) void class_stats2(
    const float* __restrict__ xs, const int* __restrict__ ys,
    int Ns, int D,
    short* __restrict__ protoC,      // bf16 [KCLS][D] class-major
    float* __restrict__ S2, float* __restrict__ mu2v, int* __restrict__ cntArr)
{
    const int c = blockIdx.x >> 2;
    const int quarter = blockIdx.x & 3;
    const int t = threadIdx.x;
    const int dim = quarter * 256 + t;          // D == 1024 assumed
    __shared__ int list[4096];
    __shared__ int lcnt;
    __shared__ float red[256];
    if (t == 0) lcnt = 0;
    __syncthreads();
    for (int s = t; s < Ns; s += 256) {
        if (ys[s] == c) list[atomicAdd(&lcnt, 1)] = s;
    }
    __syncthreads();
    const int n = lcnt;
    float a = 0.f, s2p = 0.f;
    int r = 0;
    for (; r + 4 <= n; r += 4) {                // 4-deep MLP on HBM latency
        const float x0 = xs[(size_t)list[r]     * D + dim];
        const float x1 = xs[(size_t)list[r + 1] * D + dim];
        const float x2 = xs[(size_t)list[r + 2] * D + dim];
        const float x3 = xs[(size_t)list[r + 3] * D + dim];
        a += x0 + x1 + x2 + x3;
        s2p += x0 * x0 + x1 * x1 + x2 * x2 + x3 * x3;
    }
    for (; r < n; ++r) {
        const float x = xs[(size_t)list[r] * D + dim];
        a += x; s2p += x * x;
    }
    const float inv = 1.0f / fmaxf((float)n, 0.1f);
    protoC[(size_t)c * D + dim] = f2bs(a * inv);

    red[t] = a * a; __syncthreads();
    for (int o = 128; o > 0; o >>= 1) { if (t < o) red[t] += red[t + o]; __syncthreads(); }
    if (t == 0) atomicAdd(mu2v + c, red[0]);
    __syncthreads();
    red[t] = s2p; __syncthreads();
    for (int o = 128; o > 0; o >>= 1) { if (t < o) red[t] += red[t + o]; __syncthreads(); }
    if (t == 0) {
        atomicAdd(S2 + c, red[0]);
        if (quarter == 0) cntArr[c] = n;
    }
}

// ---------------- main: MFMA dots + fused own + epilogue ----------------
// 256 blocks x 256 threads. Block = 16 queries x all 128 classes.
// Wave w computes classes [32w, 32w+32) as two 16x16x32 MFMA accumulators.
__global__ __launch_bounds__(256) void main_mfma(
    const float* __restrict__ xq, const int* __restrict__ yq,
    const int* __restrict__ ys, const int* __restrict__ posA,
    const short* __restrict__ protoC,   // bf16 [KCLS][D]
    const float* __restrict__ S2, const float* __restrict__ mu2v,
    const int* __restrict__ cntArr, const float* __restrict__ xs,
    int Nq, int D, float invNq, float* __restrict__ out)
{
    const int t    = threadIdx.x;
    const int lane = t & 63;
    const int wave = t >> 6;
    const int quad = lane >> 4;
    const int l16  = lane & 15;
    const int qb0  = blockIdx.x * QB;

    // padded LDS (stride 72 shorts = 144 B: even-bank b128 frag access)
    __shared__ short AsbS[QB * 72];
    __shared__ short BsbS[KCLS * 72];
    __shared__ float dotsS[QB * 132];   // stride 132: conflict-free C-write
    __shared__ float pn2S[KCLS];
    __shared__ float cntFS[KCLS];
    __shared__ int   cntIS[KCLS];
    __shared__ float q2S[QB], ownS[QB], diffS[QB];

    if (t < KCLS) {
        const int n = cntArr[t];
        const float cl = fmaxf((float)n, 0.1f);
        cntIS[t] = n; cntFS[t] = (float)n;
        pn2S[t] = mu2v[t] / (cl * cl);
    }

    // staging roles
    const int sq = t >> 4;            // query row 0..15 (A staging + epilogue qg)
    const int sk = (t & 15) * 4;      // k offset (floats) within chunk
    const float* aRow = xq + (size_t)(qb0 + sq) * D;
    const int p_own = posA[qb0 + sq];
    const float* sRow = xs + (size_t)p_own * D;
    const int bc  = t >> 3;           // B staging base row 0..31
    const int bk8 = (t & 7) * 8;      // B col offset (shorts)

    f32x4 acc0 = {0.f, 0.f, 0.f, 0.f};
    f32x4 acc1 = {0.f, 0.f, 0.f, 0.f};
    float q2p = 0.f, ownp = 0.f;

    for (int kb = 0; kb < D; kb += BK) {
        // issue all global loads first
        const float4 av = *(const float4*)(aRow + kb + sk);
        const float4 sv = *(const float4*)(sRow + kb + sk);
        const int4 bv0 = *(const int4*)(protoC + (size_t)(bc     ) * D + kb + bk8);
        const int4 bv1 = *(const int4*)(protoC + (size_t)(bc + 32) * D + kb + bk8);
        const int4 bv2 = *(const int4*)(protoC + (size_t)(bc + 64) * D + kb + bk8);
        const int4 bv3 = *(const int4*)(protoC + (size_t)(bc + 96) * D + kb + bk8);

        q2p += av.x * av.x + av.y * av.y + av.z * av.z + av.w * av.w;
        const float dx = av.x - sv.x, dy = av.y - sv.y, dz = av.z - sv.z, dw = av.w - sv.w;
        ownp += dx * dx + dy * dy + dz * dz + dw * dw;

        __syncthreads();   // previous iteration's frag reads complete
        {
            short4 a16;
            a16.x = f2bs(av.x); a16.y = f2bs(av.y);
            a16.z = f2bs(av.z); a16.w = f2bs(av.w);
            *(short4*)(&AsbS[sq * 72 + sk]) = a16;
        }
        *(int4*)(&BsbS[(bc     ) * 72 + bk8]) = bv0;
        *(int4*)(&BsbS[(bc + 32) * 72 + bk8]) = bv1;
        *(int4*)(&BsbS[(bc + 64) * 72 + bk8]) = bv2;
        *(int4*)(&BsbS[(bc + 96) * 72 + bk8]) = bv3;
        __syncthreads();

        #pragma unroll
        for (int ks = 0; ks < BK; ks += 32) {
            const short8 a  = *(const short8*)(&AsbS[l16 * 72 + ks + quad * 8]);
            const short8 b0 = *(const short8*)(&BsbS[(32 * wave      + l16) * 72 + ks + quad * 8]);
            const short8 b1 = *(const short8*)(&BsbS[(32 * wave + 16 + l16) * 72 + ks + quad * 8]);
            acc0 = __builtin_amdgcn_mfma_f32_16x16x32_bf16(a, b0, acc0, 0, 0, 0);
            acc1 = __builtin_amdgcn_mfma_f32_16x16x32_bf16(a, b1, acc1, 0, 0, 0);
        }
    }

    // q2/own: 16 partials per query live in lanes (t&15) of the same wave
    #pragma unroll
    for (int o = 1; o < 16; o <<= 1) {
        q2p  += __shfl_xor(q2p, o);
        ownp += __shfl_xor(ownp, o);
    }
    if ((t & 15) == 0) { q2S[sq] = q2p; ownS[sq] = ownp; }

    // scatter MFMA C-layout (col=lane&15, row=quad*4+reg) into dotsS[q][c]
    {
        const int cb = 32 * wave;
        #pragma unroll
        for (int r = 0; r < 4; ++r) {
            dotsS[(quad * 4 + r) * 132 + cb      + l16] = acc0[r];
            dotsS[(quad * 4 + r) * 132 + cb + 16 + l16] = acc1[r];
        }
    }
    __syncthreads();

    // ---------------- epilogue (verified logic from R1) ----------------
    const int qg = t >> 4;
    const int cg = t & 15;
    const int qi = qb0 + qg;
    const float q2 = q2S[qg];

    const int p  = posA[qi];
    const int ci = ys[p];
    const int cnt_i = cntIS[ci];
    const float cnt_ci  = (float)cnt_i;
    const float clip_ci = fmaxf(cnt_ci, 0.1f);
    const float dotmu   = dotsS[qg * 132 + ci] * clip_ci;   // xq . mus[ci]
    const float Ccl     = fmaxf(cnt_ci - 1.0f, 0.1f);
    const float dqM     = dotmu - q2;
    const float M2      = mu2v[ci] - 2.f * dotmu + q2;
    const float dpos2   = q2 - 2.f * dqM / Ccl + M2 / (Ccl * Ccl);
    const float d_pos   = sqrtf(fmaxf(dpos2, 0.f) + 1e-12f);

    float ld[8];
    float m = -3.0e38f;
    #pragma unroll
    for (int j = 0; j < 8; ++j) {
        const int c = cg * 8 + j;
        const float dot = dotsS[qg * 132 + c];
        const float sq_ = fmaxf(q2 + pn2S[c] - 2.f * dot, 0.f) + 1e-12f;
        float v = -sqrtf(sq_);
        if (c == ci) v = -d_pos;
        ld[j] = v;
        m = fmaxf(m, v);
    }
    #pragma unroll
    for (int o = 1; o < 16; o <<= 1) m = fmaxf(m, __shfl_xor(m, o));
    float se = 0.f;
    #pragma unroll
    for (int j = 0; j < 8; ++j) se += expf(ld[j] - m);
    #pragma unroll
    for (int o = 1; o < 16; o <<= 1) se += __shfl_xor(se, o);
    const float lse = m + logf(se);

    if (cg == 0) {
        const int cl = yq[qi];
        const int cntl_i = cntIS[cl];
        const float cntl   = (float)cntl_i;
        const float clip_l = fmaxf(cntl, 0.1f);
        const float dotmu_l = dotsS[qg * 132 + cl] * clip_l;    // xq . mus[cl]
        const float sum_sqd = cntl * q2 - 2.f * dotmu_l + S2[cl];
        const bool m_own = (cl == ci);
        const bool idxq  = (cntl_i > 1);
        const float numer = -0.5f * (sum_sqd - (m_own ? ownS[qg] : 0.f));
        const float denom = cntl - ((m_own && idxq) ? 1.f : 0.f);
        diffS[qg] = lse - numer / denom;
    }
    __syncthreads();
    if (t == 0) {
        float ssum = 0.f;
        #pragma unroll
        for (int q = 0; q < QB; ++q) ssum += diffS[q];
        atomicAdd(out, ssum * invNq);
    }
}

extern "C" void kernel_launch(void* const* d_in, const int* in_sizes, int n_in,
                              void* d_out, int out_size, void* d_ws, size_t ws_size,
                              hipStream_t stream) {
    const float* xq  = (const float*)d_in[0];
    const int*   yq  = (const int*)d_in[1];
    const float* xs  = (const float*)d_in[2];
    const int*   ys  = (const int*)d_in[3];
    const int*   pos = (const int*)d_in[4];

    const int Nq = in_sizes[1];
    const int Ns = in_sizes[3];
    const int D  = in_sizes[0] / Nq;   // 1024

    char* w = (char*)d_ws;
    short* protoC = (short*)w;  w += (size_t)KCLS * D * sizeof(short);  // bf16 [K][D]
    float* mu2v   = (float*)w;  w += KCLS * sizeof(float);
    float* S2     = (float*)w;  w += KCLS * sizeof(float);
    int*   cntA   = (int*)w;    w += KCLS * sizeof(int);

    float* out = (float*)d_out;
    hipMemsetAsync(out, 0, (size_t)out_size * sizeof(float), stream);
    hipMemsetAsync(mu2v, 0, 2 * KCLS * sizeof(float), stream);  // mu2v + S2 contiguous

    class_stats2<<<KCLS * 4, 256, 0, stream>>>(xs, ys, Ns, D, protoC, S2, mu2v, cntA);
    main_mfma<<<Nq / QB, 256, 0, stream>>>(xq, yq, ys, pos, protoC, S2, mu2v,
                                           cntA, xs, Nq, D, 1.0f / (float)Nq, out);
}

// Round 3
// 102.241 us; speedup vs baseline: 1.4622x; 1.0442x over previous
//
#include <hip/hip_runtime.h>
#include <hip/hip_bf16.h>

// MXEPLoss analytic + MFMA-bf16 dots GEMM, software-pipelined.
// Inputs: xq [Nq,D] f32, yq [Nq] i32, xs [Ns,D] f32, ys [Ns] i32, pos [Nq] i32
// Shapes fixed by bench: Nq=Ns=4096, D=1024, K=128 classes. Output: scalar f32.
//
// R3: (a) double-buffered LDS + register prefetch, ONE barrier per K-iter
//     (loads for k+1 issued after the barrier -> fly across the MFMA phase);
//     (b) no hipMemsetAsync: out zeroed by class_stats (stream-ordered before
//     main's atomicAdds), mu2/S2 via per-quarter partial slots (no atomics).

#define KCLS 128
#define QB 16
#define BK 64

typedef __attribute__((ext_vector_type(8))) short short8;
typedef __attribute__((ext_vector_type(4))) float f32x4;

__device__ __forceinline__ short f2bs(float f) {
    __hip_bfloat16 h = __float2bfloat16(f);
    short s; __builtin_memcpy(&s, &h, 2); return s;
}

// ---------------- class stats: 512 blocks = 128 classes x 4 dim-quarters ----
__global__ __launch_bounds__(256) void class_stats2(
    const float* __restrict__ xs, const int* __restrict__ ys,
    int Ns, int D,
    short* __restrict__ protoC,      // bf16 [KCLS][D] class-major
    float* __restrict__ S2part,      // [KCLS][4]
    float* __restrict__ mu2part,     // [KCLS][4]
    int* __restrict__ cntArr, float* __restrict__ out)
{
    const int c = blockIdx.x >> 2;
    const int quarter = blockIdx.x & 3;
    const int t = threadIdx.x;
    const int dim = quarter * 256 + t;          // D == 1024 assumed
    if (blockIdx.x == 0 && t == 0) out[0] = 0.f;   // main runs after us on the stream
    __shared__ int list[4096];
    __shared__ int lcnt;
    __shared__ float red[256];
    if (t == 0) lcnt = 0;
    __syncthreads();
    for (int s = t; s < Ns; s += 256) {
        if (ys[s] == c) list[atomicAdd(&lcnt, 1)] = s;
    }
    __syncthreads();
    const int n = lcnt;
    float a = 0.f, s2p = 0.f;
    int r = 0;
    for (; r + 4 <= n; r += 4) {                // 4-deep MLP on load latency
        const float x0 = xs[(size_t)list[r]     * D + dim];
        const float x1 = xs[(size_t)list[r + 1] * D + dim];
        const float x2 = xs[(size_t)list[r + 2] * D + dim];
        const float x3 = xs[(size_t)list[r + 3] * D + dim];
        a += x0 + x1 + x2 + x3;
        s2p += x0 * x0 + x1 * x1 + x2 * x2 + x3 * x3;
    }
    for (; r < n; ++r) {
        const float x = xs[(size_t)list[r] * D + dim];
        a += x; s2p += x * x;
    }
    const float inv = 1.0f / fmaxf((float)n, 0.1f);
    protoC[(size_t)c * D + dim] = f2bs(a * inv);

    red[t] = a * a; __syncthreads();
    for (int o = 128; o > 0; o >>= 1) { if (t < o) red[t] += red[t + o]; __syncthreads(); }
    if (t == 0) mu2part[c * 4 + quarter] = red[0];
    __syncthreads();
    red[t] = s2p; __syncthreads();
    for (int o = 128; o > 0; o >>= 1) { if (t < o) red[t] += red[t + o]; __syncthreads(); }
    if (t == 0) {
        S2part[c * 4 + quarter] = red[0];
        if (quarter == 0) cntArr[c] = n;
    }
}

// ---------------- main: pipelined MFMA dots + fused own + epilogue ----------
// 256 blocks x 256 threads. Block = 16 queries x all 128 classes.
// Wave w computes classes [32w, 32w+32) as two 16x16x32 MFMA accumulators.
__global__ __launch_bounds__(256) void main_mfma(
    const float* __restrict__ xq, const int* __restrict__ yq,
    const int* __restrict__ ys, const int* __restrict__ posA,
    const short* __restrict__ protoC,   // bf16 [KCLS][D]
    const float* __restrict__ S2part, const float* __restrict__ mu2part,
    const int* __restrict__ cntArr, const float* __restrict__ xs,
    int Nq, int D, float invNq, float* __restrict__ out)
{
    const int t    = threadIdx.x;
    const int lane = t & 63;
    const int wave = t >> 6;
    const int quad = lane >> 4;
    const int l16  = lane & 15;
    const int qb0  = blockIdx.x * QB;

    // padded LDS (stride 72 shorts = 144 B: even-bank b128 frag access)
    __shared__ short Asb[2][QB * 72];
    __shared__ short Bsb[2][KCLS * 72];
    __shared__ float dotsS[QB * 132];   // stride 132: conflict-free C-write
    __shared__ float pn2S[KCLS];
    __shared__ float mu2S[KCLS];
    __shared__ float S2S[KCLS];
    __shared__ int   cntIS[KCLS];
    __shared__ float q2S[QB], ownS[QB], diffS[QB];

    if (t < KCLS) {
        const int n = cntArr[t];
        const float cl = fmaxf((float)n, 0.1f);
        const float m2 = mu2part[t * 4] + mu2part[t * 4 + 1]
                       + mu2part[t * 4 + 2] + mu2part[t * 4 + 3];
        cntIS[t] = n;
        mu2S[t]  = m2;
        pn2S[t]  = m2 / (cl * cl);
        S2S[t]   = S2part[t * 4] + S2part[t * 4 + 1]
                 + S2part[t * 4 + 2] + S2part[t * 4 + 3];
    }

    // staging roles
    const int sq = t >> 4;            // query row 0..15 (A staging + epilogue qg)
    const int sk = (t & 15) * 4;      // k offset (floats) within chunk
    const float* aRow = xq + (size_t)(qb0 + sq) * D;
    const float* sRow = xs + (size_t)posA[qb0 + sq] * D;
    const int bc  = t >> 3;           // B staging base row 0..31
    const int bk8 = (t & 7) * 8;      // B col offset (shorts)
    const short* bBase = protoC + (size_t)bc * D + bk8;
    const size_t bStride = (size_t)32 * D;

    f32x4 acc0 = {0.f, 0.f, 0.f, 0.f};
    f32x4 acc1 = {0.f, 0.f, 0.f, 0.f};
    float q2p = 0.f, ownp = 0.f;

    // prologue: loads for chunk 0
    float4 av = *(const float4*)(aRow + sk);
    float4 sv = *(const float4*)(sRow + sk);
    int4 bv0 = *(const int4*)(bBase);
    int4 bv1 = *(const int4*)(bBase + bStride);
    int4 bv2 = *(const int4*)(bBase + 2 * bStride);
    int4 bv3 = *(const int4*)(bBase + 3 * bStride);

    const int aro = l16 * 72 + quad * 8;             // A frag read offset
    const int br0 = (32 * wave      + l16) * 72 + quad * 8;
    const int br1 = (32 * wave + 16 + l16) * 72 + quad * 8;

    for (int it = 0; it < 16; ++it) {
        short* Ab = Asb[it & 1];
        short* Bb = Bsb[it & 1];
        // stage current registers -> LDS[buf]
        {
            short4 a16;
            a16.x = f2bs(av.x); a16.y = f2bs(av.y);
            a16.z = f2bs(av.z); a16.w = f2bs(av.w);
            *(short4*)(&Ab[sq * 72 + sk]) = a16;
        }
        *(int4*)(&Bb[bc * 72 + bk8]) = bv0;
        *(int4*)(&Bb[(bc + 32) * 72 + bk8]) = bv1;
        *(int4*)(&Bb[(bc + 64) * 72 + bk8]) = bv2;
        *(int4*)(&Bb[(bc + 96) * 72 + bk8]) = bv3;
        // scalar math on current A regs (fills barrier-wait time)
        q2p += av.x * av.x + av.y * av.y + av.z * av.z + av.w * av.w;
        {
            const float dx = av.x - sv.x, dy = av.y - sv.y;
            const float dz = av.z - sv.z, dw = av.w - sv.w;
            ownp += dx * dx + dy * dy + dz * dz + dw * dw;
        }
        __syncthreads();
        if (it < 15) {   // prefetch chunk it+1 (flies across the MFMA phase)
            const int kb = (it + 1) * BK;
            av = *(const float4*)(aRow + kb + sk);
            sv = *(const float4*)(sRow + kb + sk);
            bv0 = *(const int4*)(bBase + kb);
            bv1 = *(const int4*)(bBase + bStride + kb);
            bv2 = *(const int4*)(bBase + 2 * bStride + kb);
            bv3 = *(const int4*)(bBase + 3 * bStride + kb);
        }
        #pragma unroll
        for (int ks = 0; ks < BK; ks += 32) {
            const short8 a  = *(const short8*)(&Ab[aro + ks]);
            const short8 b0 = *(const short8*)(&Bb[br0 + ks]);
            const short8 b1 = *(const short8*)(&Bb[br1 + ks]);
            acc0 = __builtin_amdgcn_mfma_f32_16x16x32_bf16(a, b0, acc0, 0, 0, 0);
            acc1 = __builtin_amdgcn_mfma_f32_16x16x32_bf16(a, b1, acc1, 0, 0, 0);
        }
    }

    // q2/own: 16 partials per query live in lanes (t&15) of the same wave
    #pragma unroll
    for (int o = 1; o < 16; o <<= 1) {
        q2p  += __shfl_xor(q2p, o);
        ownp += __shfl_xor(ownp, o);
    }
    if ((t & 15) == 0) { q2S[sq] = q2p; ownS[sq] = ownp; }

    // scatter MFMA C-layout (col=lane&15, row=quad*4+reg) into dotsS[q][c]
    {
        const int cb = 32 * wave;
        #pragma unroll
        for (int r = 0; r < 4; ++r) {
            dotsS[(quad * 4 + r) * 132 + cb      + l16] = acc0[r];
            dotsS[(quad * 4 + r) * 132 + cb + 16 + l16] = acc1[r];
        }
    }
    __syncthreads();

    // ---------------- epilogue (verified logic from R1/R2) ----------------
    const int qg = t >> 4;
    const int cg = t & 15;
    const int qi = qb0 + qg;
    const float q2 = q2S[qg];

    const int p  = posA[qi];
    const int ci = ys[p];
    const int cnt_i = cntIS[ci];
    const float cnt_ci  = (float)cnt_i;
    const float clip_ci = fmaxf(cnt_ci, 0.1f);
    const float dotmu   = dotsS[qg * 132 + ci] * clip_ci;   // xq . mus[ci]
    const float Ccl     = fmaxf(cnt_ci - 1.0f, 0.1f);
    const float dqM     = dotmu - q2;
    const float M2      = mu2S[ci] - 2.f * dotmu + q2;
    const float dpos2   = q2 - 2.f * dqM / Ccl + M2 / (Ccl * Ccl);
    const float d_pos   = sqrtf(fmaxf(dpos2, 0.f) + 1e-12f);

    float ld[8];
    float m = -3.0e38f;
    #pragma unroll
    for (int j = 0; j < 8; ++j) {
        const int c = cg * 8 + j;
        const float dot = dotsS[qg * 132 + c];
        const float sq_ = fmaxf(q2 + pn2S[c] - 2.f * dot, 0.f) + 1e-12f;
        float v = -sqrtf(sq_);
        if (c == ci) v = -d_pos;
        ld[j] = v;
        m = fmaxf(m, v);
    }
    #pragma unroll
    for (int o = 1; o < 16; o <<= 1) m = fmaxf(m, __shfl_xor(m, o));
    float se = 0.f;
    #pragma unroll
    for (int j = 0; j < 8; ++j) se += expf(ld[j] - m);
    #pragma unroll
    for (int o = 1; o < 16; o <<= 1) se += __shfl_xor(se, o);
    const float lse = m + logf(se);

    if (cg == 0) {
        const int cl = yq[qi];
        const int cntl_i = cntIS[cl];
        const float cntl = (float)cntl_i;
        const float dotmu_l = dotsS[qg * 132 + cl] * fmaxf(cntl, 0.1f); // xq . mus[cl]
        const float sum_sqd = cntl * q2 - 2.f * dotmu_l + S2S[cl];
        const bool m_own = (cl == ci);
        const bool idxq  = (cntl_i > 1);
        const float numer = -0.5f * (sum_sqd - (m_own ? ownS[qg] : 0.f));
        const float denom = cntl - ((m_own && idxq) ? 1.f : 0.f);
        diffS[qg] = lse - numer / denom;
    }
    __syncthreads();
    if (t == 0) {
        float ssum = 0.f;
        #pragma unroll
        for (int q = 0; q < QB; ++q) ssum += diffS[q];
        atomicAdd(out, ssum * invNq);
    }
}

extern "C" void kernel_launch(void* const* d_in, const int* in_sizes, int n_in,
                              void* d_out, int out_size, void* d_ws, size_t ws_size,
                              hipStream_t stream) {
    const float* xq  = (const float*)d_in[0];
    const int*   yq  = (const int*)d_in[1];
    const float* xs  = (const float*)d_in[2];
    const int*   ys  = (const int*)d_in[3];
    const int*   pos = (const int*)d_in[4];

    const int Nq = in_sizes[1];
    const int Ns = in_sizes[3];
    const int D  = in_sizes[0] / Nq;   // 1024

    char* w = (char*)d_ws;
    short* protoC  = (short*)w;  w += (size_t)KCLS * D * sizeof(short);  // bf16 [K][D]
    float* mu2part = (float*)w;  w += (size_t)KCLS * 4 * sizeof(float);
    float* S2part  = (float*)w;  w += (size_t)KCLS * 4 * sizeof(float);
    int*   cntA    = (int*)w;    w += KCLS * sizeof(int);

    float* out = (float*)d_out;

    class_stats2<<<KCLS * 4, 256, 0, stream>>>(xs, ys, Ns, D, protoC,
                                               S2part, mu2part, cntA, out);
    main_mfma<<<Nq / QB, 256, 0, stream>>>(xq, yq, ys, pos, protoC, S2part, mu2part,
                                           cntA, xs, Nq, D, 1.0f / (float)Nq, out);
}